// Round 17
// baseline (65.616 us; speedup 1.0000x reference)
//
#include <hip/hip_runtime.h>

// RoIAlign (torchvision semantics, aligned=false, sampling_ratio=2)
// features: [N=2, C=256, H=200, W=200] f32, rois: [K,5], out: [K,256,7,7] f32
constexpr int C = 256, H = 200, W = 200, NB = 2;
constexpr int PH = 7, PW = 7;
constexpr int NS = 14;             // samples per axis (PH*2)
constexpr float SCALE = 0.125f;
// transposed tensor: T[cg:8][nb:2][y][x][32ch] f16 — 64B per (pixel,cgroup) = 1 line
constexpr int CG = 32, NCG = C / CG;
constexpr int TY = 4;              // y-rows per transpose block
constexpr int TS = 20;             // corner-table bin stride: 16B-aligned for b128, <=2-way banks
// fallback (R4) tiling
constexpr int CGF = 8, NGROUPF = C / CGF;

typedef float    f32x4 __attribute__((ext_vector_type(4)));
typedef _Float16 h2    __attribute__((ext_vector_type(2)));

// ---- batch compaction: idx[0..c0) = batch-0 rois, idx[c0..K) = batch-1 rois (order don't-care) ----
__global__ __launch_bounds__(256) void compact_kernel(
    const float* __restrict__ rois, int* __restrict__ idx, uint* __restrict__ cnt, int K)
{
    int i = blockIdx.x * 256 + threadIdx.x;
    if (i >= K) return;
    int b = (int)rois[(size_t)i * 5];
    if (b == 0) { uint p = atomicAdd(&cnt[0], 1u); idx[p] = i; }
    else        { uint p = atomicAdd(&cnt[1], 1u); idx[K - 1 - (int)p] = i; }
}

// ---- transpose: NCHW f32 -> cgroup-tiled NHWC f16 (TY=4, REGULAR stores: T must stay cache-warm
//      for the consumer gather — NT stores here cost the gather +16us (R15 lesson)) ----
__global__ __launch_bounds__(256) void transpose_kernel(
    const float* __restrict__ feat, ushort* __restrict__ T)
{
    __shared__ float tile[TY][32][36];   // [y][x][ch], pad 36 keeps float4 reads 16B-aligned
    int B = blockIdx.x;
    int xt = B % 7; int tmp = B / 7;
    int yt = tmp % (H / TY); tmp /= (H / TY);
    int nb = tmp & 1; int cg = tmp >> 1;
    int x0 = xt * 32, y0 = yt * TY;
    int xw = min(32, W - x0);

    int t = threadIdx.x;
    {
        int cl = t >> 3, xi = (t & 7) * 4;
        if (xi < xw) {
            const float* src = feat + (((size_t)nb * C + cg * CG + cl) * H + y0) * W + x0 + xi;
            #pragma unroll
            for (int yy = 0; yy < TY; ++yy) {
                float4 v = *reinterpret_cast<const float4*>(src + yy * W);
                tile[yy][xi + 0][cl] = v.x; tile[yy][xi + 1][cl] = v.y;
                tile[yy][xi + 2][cl] = v.z; tile[yy][xi + 3][cl] = v.w;
            }
        }
    }
    __syncthreads();
    int xl = t >> 3, c4 = (t & 7) * 4;
    if (xl < xw) {
        #pragma unroll
        for (int yy = 0; yy < TY; ++yy) {
            float4 v = *reinterpret_cast<const float4*>(&tile[yy][xl][c4]);
            uint2 o;
            o.x = __builtin_bit_cast(uint, __builtin_amdgcn_cvt_pkrtz(v.x, v.y));
            o.y = __builtin_bit_cast(uint, __builtin_amdgcn_cvt_pkrtz(v.z, v.w));
            ushort* dst = T + ((((size_t)cg * NB + nb) * H + (y0 + yy)) * W + (x0 + xl)) * CG + c4;
            *reinterpret_cast<uint2*>(dst) = o;   // regular store: keep T in L2/L3
        }
    }
}

// ---- gather: compacted roi list (zero phantom blocks) + cheap 2-phase LDS table
//      + conflict-free reads + MLP-16 + packed f16 FMA ----
__global__ __launch_bounds__(256) void gather_kernel(
    const ushort* __restrict__ T, const float* __restrict__ rois,
    const int* __restrict__ idx, float* __restrict__ out, int K)
{
    __shared__ int   s_ylo[NS], s_yhi[NS], s_xlo[NS], s_xhi[NS];
    __shared__ float s_wy[NS][2], s_wx[NS][2];
    __shared__ int   s_off[49 * TS];
    __shared__ uint  s_wgt[49 * TS];   // packed h2(w,w)
    __shared__ float s_out[CG * 49];   // [ch][bin] f32

    int B  = blockIdx.x;
    int cg = B & 7;                 // cgroup pinned to XCD (consecutive blocks round-robin XCDs)
    int j  = B >> 3;
    int k  = idx[j];                // batch-contiguous order keeps per-XCD L2 slice resident

    const float* r = rois + (size_t)k * 5;
    int b = (int)r[0];

    float x1 = r[1]*SCALE, y1 = r[2]*SCALE, x2 = r[3]*SCALE, y2 = r[4]*SCALE;
    float bw = fmaxf(x2 - x1, 1.0f) * (1.0f / PW);
    float bh = fmaxf(y2 - y1, 1.0f) * (1.0f / PH);

    int t = threadIdx.x;
    // phase 1: axis tables (heavy math 14x per axis, not 784x)
    if (t < NS) {                           // y axis
        int ph = t >> 1, s = t & 1;
        float y = y1 + (float)ph * bh + ((float)s + 0.5f) * bh * 0.5f;
        bool v = (y >= -1.0f) && (y <= (float)H);
        float yc = fmaxf(y, 0.0f);
        int lo = (int)yc, hi;
        if (lo >= H - 1) { lo = H - 1; hi = H - 1; yc = (float)(H - 1); }
        else             { hi = lo + 1; }
        float l = yc - (float)lo;
        s_ylo[t] = lo; s_yhi[t] = hi;
        s_wy[t][0] = v ? 1.0f - l : 0.0f;   // pairs with ylo
        s_wy[t][1] = v ? l        : 0.0f;   // pairs with yhi
    } else if (t >= 64 && t < 64 + NS) {    // x axis
        int i = t - 64, pw = i >> 1, s = i & 1;
        float x = x1 + (float)pw * bw + ((float)s + 0.5f) * bw * 0.5f;
        bool v = (x >= -1.0f) && (x <= (float)W);
        float xc = fmaxf(x, 0.0f);
        int lo = (int)xc, hi;
        if (lo >= W - 1) { lo = W - 1; hi = W - 1; xc = (float)(W - 1); }
        else             { hi = lo + 1; }
        float l = xc - (float)lo;
        s_xlo[i] = lo; s_xhi[i] = hi;
        s_wx[i][0] = v ? 1.0f - l : 0.0f;
        s_wx[i][1] = v ? l        : 0.0f;
    }
    __syncthreads();

    // phase 2: cheap combine, 784 entries; weight pre-packed as h2(w,w)
    for (int e = t; e < 49 * 16; e += 256) {
        int bin = e >> 4, cr = e & 15;
        int ph = bin / 7, pw = bin - ph * 7;
        int sy = (cr >> 3) & 1, sx = (cr >> 2) & 1, cy = (cr >> 1) & 1, cx = cr & 1;
        int ysi = 2 * ph + sy, xsi = 2 * pw + sx;
        int row = cy ? s_yhi[ysi] : s_ylo[ysi];
        int col = cx ? s_xhi[xsi] : s_xlo[xsi];
        float w = s_wy[ysi][cy] * s_wx[xsi][cx] * 0.25f;
        s_off[bin * TS + cr] = (row * W + col) * CG;
        s_wgt[bin * TS + cr] = __builtin_bit_cast(uint, __builtin_amdgcn_cvt_pkrtz(w, w));
    }
    __syncthreads();

    if (t < 49 * 4) {               // 4 lanes per bin, each owns 8 channels (16B of the 64B line)
        int bin = t >> 2, q = t & 3;
        const int*  po = s_off + bin * TS;
        const uint* pg = s_wgt + bin * TS;
        // table reads: 4+4 ds_read_b128, 16B-aligned (TS=20), <=2-way banks (free)
        int4  o0 = *reinterpret_cast<const int4*>(po + 0);
        int4  o1 = *reinterpret_cast<const int4*>(po + 4);
        int4  o2 = *reinterpret_cast<const int4*>(po + 8);
        int4  o3 = *reinterpret_cast<const int4*>(po + 12);
        uint4 w0 = *reinterpret_cast<const uint4*>(pg + 0);
        uint4 w1 = *reinterpret_cast<const uint4*>(pg + 4);
        uint4 w2 = *reinterpret_cast<const uint4*>(pg + 8);
        uint4 w3 = *reinterpret_cast<const uint4*>(pg + 12);

        const ushort* slab = T + ((size_t)(cg * NB + b) * H * W) * CG + q * 8;
        // issue ALL 16 corner loads before consuming (MLP=16)
        uint4 d0  = *reinterpret_cast<const uint4*>(slab + o0.x);
        uint4 d1  = *reinterpret_cast<const uint4*>(slab + o0.y);
        uint4 d2  = *reinterpret_cast<const uint4*>(slab + o0.z);
        uint4 d3  = *reinterpret_cast<const uint4*>(slab + o0.w);
        uint4 d4  = *reinterpret_cast<const uint4*>(slab + o1.x);
        uint4 d5  = *reinterpret_cast<const uint4*>(slab + o1.y);
        uint4 d6  = *reinterpret_cast<const uint4*>(slab + o1.z);
        uint4 d7  = *reinterpret_cast<const uint4*>(slab + o1.w);
        uint4 d8  = *reinterpret_cast<const uint4*>(slab + o2.x);
        uint4 d9  = *reinterpret_cast<const uint4*>(slab + o2.y);
        uint4 d10 = *reinterpret_cast<const uint4*>(slab + o2.z);
        uint4 d11 = *reinterpret_cast<const uint4*>(slab + o2.w);
        uint4 d12 = *reinterpret_cast<const uint4*>(slab + o3.x);
        uint4 d13 = *reinterpret_cast<const uint4*>(slab + o3.y);
        uint4 d14 = *reinterpret_cast<const uint4*>(slab + o3.z);
        uint4 d15 = *reinterpret_cast<const uint4*>(slab + o3.w);

        h2 a01 = {0, 0}, a23 = {0, 0}, a45 = {0, 0}, a67 = {0, 0};
        // 4x v_pk_fma_f16 per corner: 8 channels, no unpack
        #define H2(u) (__builtin_bit_cast(h2, (uint)(u)))
        #define CORNER(dd, wu) { h2 wpk = H2(wu);                  \
            a01 += H2((dd).x) * wpk;  a23 += H2((dd).y) * wpk;     \
            a45 += H2((dd).z) * wpk;  a67 += H2((dd).w) * wpk; }
        CORNER(d0,  w0.x) CORNER(d1,  w0.y) CORNER(d2,  w0.z) CORNER(d3,  w0.w)
        CORNER(d4,  w1.x) CORNER(d5,  w1.y) CORNER(d6,  w1.z) CORNER(d7,  w1.w)
        CORNER(d8,  w2.x) CORNER(d9,  w2.y) CORNER(d10, w2.z) CORNER(d11, w2.w)
        CORNER(d12, w3.x) CORNER(d13, w3.y) CORNER(d14, w3.z) CORNER(d15, w3.w)
        #undef CORNER
        #undef H2

        float* so = s_out + (8 * q) * 49 + bin;
        so[0*49] = (float)a01.x; so[1*49] = (float)a01.y;
        so[2*49] = (float)a23.x; so[3*49] = (float)a23.y;
        so[4*49] = (float)a45.x; so[5*49] = (float)a45.y;
        so[6*49] = (float)a67.x; so[7*49] = (float)a67.y;
    }
    __syncthreads();

    // coalesced contiguous write: out[k][cg*32 .. cg*32+31][0..48] (terminal output -> NT ok)
    float* oslab = out + ((size_t)k * C + cg * CG) * (PH * PW);
    for (int i4 = t; i4 < (CG * 49) / 4; i4 += 256) {
        f32x4 v = *reinterpret_cast<const f32x4*>(s_out + 4 * i4);
        __builtin_nontemporal_store(v, reinterpret_cast<f32x4*>(oslab + 4 * i4));
    }
}

// ---------------- fallback (R4 kernel) if workspace too small ----------------
struct __attribute__((packed, aligned(4))) f2 { float a, b; };

__global__ __launch_bounds__(256) void roi_align_fallback(
    const float* __restrict__ feat, const float* __restrict__ rois,
    float* __restrict__ out, int K)
{
    __shared__ int   s_ylo[NS], s_yhi[NS];
    __shared__ float s_wy[NS][2];
    __shared__ int   s_xb[NS];
    __shared__ float s_wx[NS][2];

    int B   = blockIdx.x;
    int xcd = B & 7;
    int j   = B >> 3;
    int p   = j / K, k = j - p * K;
    int cb  = (p * 8 + xcd) * CGF;

    const float* r = rois + (size_t)k * 5;
    int   b  = (int)r[0];
    float x1 = r[1]*SCALE, y1 = r[2]*SCALE, x2 = r[3]*SCALE, y2 = r[4]*SCALE;
    float bw = fmaxf(x2 - x1, 1.0f) * (1.0f / PW);
    float bh = fmaxf(y2 - y1, 1.0f) * (1.0f / PH);

    int t = threadIdx.x;
    if (t < NS) {
        int ph = t >> 1, s = t & 1;
        float y = y1 + (float)ph * bh + ((float)s + 0.5f) * bh * 0.5f;
        bool v = (y >= -1.0f) && (y <= (float)H);
        float yc = fmaxf(y, 0.0f);
        int lo = (int)yc, hi;
        if (lo >= H - 1) { lo = H - 1; hi = H - 1; yc = (float)(H - 1); }
        else             { hi = lo + 1; }
        float l = yc - (float)lo;
        s_ylo[t] = lo; s_yhi[t] = hi;
        s_wy[t][0] = v ? 1.0f - l : 0.0f;
        s_wy[t][1] = v ? l        : 0.0f;
    } else if (t >= 64 && t < 64 + NS) {
        int i = t - 64, pw = i >> 1, s = i & 1;
        float x = x1 + (float)pw * bw + ((float)s + 0.5f) * bw * 0.5f;
        bool v = (x >= -1.0f) && (x <= (float)W);
        float xc = fmaxf(x, 0.0f);
        int lo = (int)xc;
        if (lo >= W - 1) {
            s_xb[i] = W - 2; s_wx[i][0] = 0.0f; s_wx[i][1] = v ? 1.0f : 0.0f;
        } else {
            float l = xc - (float)lo;
            s_xb[i] = lo; s_wx[i][0] = v ? 1.0f - l : 0.0f; s_wx[i][1] = v ? l : 0.0f;
        }
    }
    __syncthreads();

    const float* img = feat + (size_t)b * (C * H * W);
    float* out_base = out + ((size_t)k * C + cb) * (PH * PW);

    for (int i = t; i < CGF * PH * PW; i += 256) {
        int cl  = i / (PH * PW);
        int bin = i - cl * (PH * PW);
        int ph  = bin / PW;
        int pw  = bin - ph * PW;
        const float* plane = img + (size_t)(cb + cl) * (H * W);

        float acc = 0.0f;
        #pragma unroll
        for (int sy = 0; sy < 2; ++sy) {
            int ysi = 2 * ph + sy;
            const float* rlo = plane + s_ylo[ysi] * W;
            const float* rhi = plane + s_yhi[ysi] * W;
            float hy = s_wy[ysi][0], ly = s_wy[ysi][1];
            #pragma unroll
            for (int sx = 0; sx < 2; ++sx) {
                int xsi = 2 * pw + sx;
                int xb = s_xb[xsi];
                float w0 = s_wx[xsi][0], w1 = s_wx[xsi][1];
                f2 vlo = *reinterpret_cast<const f2*>(rlo + xb);
                f2 vhi = *reinterpret_cast<const f2*>(rhi + xb);
                acc += hy * (w0 * vlo.a + w1 * vlo.b)
                     + ly * (w0 * vhi.a + w1 * vhi.b);
            }
        }
        __builtin_nontemporal_store(acc * 0.25f, &out_base[i]);
    }
}

extern "C" void kernel_launch(void* const* d_in, const int* in_sizes, int n_in,
                              void* d_out, int out_size, void* d_ws, size_t ws_size,
                              hipStream_t stream) {
    const float* feat = (const float*)d_in[0];
    const float* rois = (const float*)d_in[1];
    float* out = (float*)d_out;
    int K = in_sizes[1] / 5;

    size_t t_bytes = (size_t)NCG * NB * H * W * CG * sizeof(ushort);  // 40,960,000
    size_t need = t_bytes + (size_t)K * sizeof(int) + 2 * sizeof(uint);
    if (ws_size >= need) {
        ushort* T  = (ushort*)d_ws;
        int*   idx = (int*)((char*)d_ws + t_bytes);
        uint*  cnt = (uint*)(idx + K);
        hipMemsetAsync(cnt, 0, 2 * sizeof(uint), stream);
        compact_kernel<<<(K + 255) / 256, 256, 0, stream>>>(rois, idx, cnt, K);
        int tblocks = NCG * NB * (H / TY) * 7;   // 5600
        transpose_kernel<<<tblocks, 256, 0, stream>>>(feat, T);
        gather_kernel<<<K * NCG, 256, 0, stream>>>(T, rois, idx, out, K);  // K*8, zero phantoms
    } else {
        roi_align_fallback<<<K * NGROUPF, 256, 0, stream>>>(feat, rois, out, K);
    }
}

// Round 18
// 57.014 us; speedup vs baseline: 1.1509x; 1.1509x over previous
//
#include <hip/hip_runtime.h>

// RoIAlign (torchvision semantics, aligned=false, sampling_ratio=2)
// features: [N=2, C=256, H=200, W=200] f32, rois: [K,5], out: [K,256,7,7] f32
constexpr int C = 256, H = 200, W = 200, NB = 2;
constexpr int PH = 7, PW = 7;
constexpr int NS = 14;             // fallback only
constexpr float SCALE = 0.125f;
// transposed tensor: T[cg:8][nb:2][y][x][32ch] f16 — 64B per (pixel,cgroup) = 1 line
constexpr int CG = 32, NCG = C / CG;
// fallback (R4) tiling
constexpr int CGF = 8, NGROUPF = C / CGF;

typedef float    f32x4 __attribute__((ext_vector_type(4)));
typedef _Float16 h2    __attribute__((ext_vector_type(2)));

// ---- transpose: NCHW f32 -> cgroup-tiled NHWC f16 (R14 form: regular stores — NT on a
//      producer->consumer intermediate costs the consumer +16us, R15 lesson) ----
__global__ __launch_bounds__(256) void transpose_kernel(
    const float* __restrict__ feat, ushort* __restrict__ T)
{
    __shared__ float tile[32][36];   // [x][ch], pad 36 keeps float4 reads 16B-aligned
    int B = blockIdx.x;
    int xt = B % 7; int tmp = B / 7;
    int y  = tmp % H; tmp /= H;
    int nb = tmp & 1; int cg = tmp >> 1;
    int x0 = xt * 32;
    int xw = min(32, W - x0);

    int t = threadIdx.x;
    {
        int cl = t >> 3, xi = (t & 7) * 4;
        if (xi < xw) {
            const float* src = feat + (((size_t)nb * C + cg * CG + cl) * H + y) * W + x0 + xi;
            float4 v = *reinterpret_cast<const float4*>(src);
            tile[xi + 0][cl] = v.x; tile[xi + 1][cl] = v.y;
            tile[xi + 2][cl] = v.z; tile[xi + 3][cl] = v.w;
        }
    }
    __syncthreads();
    int xl = t >> 3, c4 = (t & 7) * 4;
    if (xl < xw) {
        float4 v = *reinterpret_cast<const float4*>(&tile[xl][c4]);
        uint2 o;
        o.x = __builtin_bit_cast(uint, __builtin_amdgcn_cvt_pkrtz(v.x, v.y));
        o.y = __builtin_bit_cast(uint, __builtin_amdgcn_cvt_pkrtz(v.z, v.w));
        ushort* dst = T + ((((size_t)cg * NB + nb) * H + y) * W + (x0 + xl)) * CG + c4;
        *reinterpret_cast<uint2*>(dst) = o;   // regular store: keep T cache-warm for gather
    }
}

// ---- gather: ALL-REGISTER corner table (no LDS table, no pre-load barriers) + MLP-16
//      + packed f16 FMA. Per (bin,q) thread: 2 y-samples + 2 x-samples derive all 16 corners. ----
__global__ __launch_bounds__(256) void gather_kernel(
    const ushort* __restrict__ T, const float* __restrict__ rois,
    float* __restrict__ out, int K)
{
    __shared__ float s_out[CG * 49];   // [ch][bin] f32 — only LDS use

    int B  = blockIdx.x;
    int cg = B & 7;                 // cgroup pinned to XCD (consecutive blocks round-robin XCDs)
    int j  = B >> 3;
    int p  = j / K, k = j - p * K;  // phase p = batch slice; per-XCD L2 slice = 2.56MB resident

    const float* r = rois + (size_t)k * 5;
    int b = (int)r[0];
    if (b != p) return;             // block-uniform exit before the barrier (phantoms are cheap, R17)

    int t = threadIdx.x;
    if (t < 49 * 4) {               // 4 lanes per bin, each owns 8 channels (16B of the 64B line)
        int bin = t >> 2, q = t & 3;
        int ph = bin / 7, pw = bin - ph * 7;

        float x1 = r[1]*SCALE, y1 = r[2]*SCALE, x2 = r[3]*SCALE, y2 = r[4]*SCALE;
        float bw = fmaxf(x2 - x1, 1.0f) * (1.0f / PW);
        float bh = fmaxf(y2 - y1, 1.0f) * (1.0f / PH);

        // axis terms in registers: 2 samples per axis
        int   yr[2][2]; float wy[2][2];
        int   xr[2][2]; float wx[2][2];
        #pragma unroll
        for (int s = 0; s < 2; ++s) {
            float y = y1 + (float)ph * bh + ((float)s + 0.5f) * bh * 0.5f;
            bool v = (y >= -1.0f) && (y <= (float)H);
            float yc = fmaxf(y, 0.0f);
            int lo = (int)yc, hi;
            if (lo >= H - 1) { lo = H - 1; hi = H - 1; yc = (float)(H - 1); }
            else             { hi = lo + 1; }
            float l = yc - (float)lo;
            yr[s][0] = lo; yr[s][1] = hi;
            wy[s][0] = v ? 1.0f - l : 0.0f;
            wy[s][1] = v ? l        : 0.0f;
        }
        #pragma unroll
        for (int s = 0; s < 2; ++s) {
            float x = x1 + (float)pw * bw + ((float)s + 0.5f) * bw * 0.5f;
            bool v = (x >= -1.0f) && (x <= (float)W);
            float xc = fmaxf(x, 0.0f);
            int lo = (int)xc, hi;
            if (lo >= W - 1) { lo = W - 1; hi = W - 1; xc = (float)(W - 1); }
            else             { hi = lo + 1; }
            float l = xc - (float)lo;
            xr[s][0] = lo; xr[s][1] = hi;
            wx[s][0] = v ? 1.0f - l : 0.0f;
            wx[s][1] = v ? l        : 0.0f;
        }

        // 16 corner offsets + packed weights, fully unrolled (static indices -> registers)
        int  offv[16];
        uint wgtv[16];
        #pragma unroll
        for (int cr = 0; cr < 16; ++cr) {
            int sy = (cr >> 3) & 1, sx = (cr >> 2) & 1, cy = (cr >> 1) & 1, cx = cr & 1;
            offv[cr] = (yr[sy][cy] * W + xr[sx][cx]) * CG;
            float w = wy[sy][cy] * wx[sx][cx] * 0.25f;
            wgtv[cr] = __builtin_bit_cast(uint, __builtin_amdgcn_cvt_pkrtz(w, w));
        }

        const ushort* slab = T + ((size_t)(cg * NB + p) * H * W) * CG + q * 8;
        // issue ALL 16 corner loads (MLP=16) — no barriers, no LDS on the path
        uint4 d[16];
        #pragma unroll
        for (int cr = 0; cr < 16; ++cr)
            d[cr] = *reinterpret_cast<const uint4*>(slab + offv[cr]);

        h2 a01 = {0, 0}, a23 = {0, 0}, a45 = {0, 0}, a67 = {0, 0};
        #define H2(u) (__builtin_bit_cast(h2, (uint)(u)))
        #pragma unroll
        for (int cr = 0; cr < 16; ++cr) {
            h2 wpk = H2(wgtv[cr]);
            a01 += H2(d[cr].x) * wpk;  a23 += H2(d[cr].y) * wpk;
            a45 += H2(d[cr].z) * wpk;  a67 += H2(d[cr].w) * wpk;
        }
        #undef H2

        float* so = s_out + (8 * q) * 49 + bin;
        so[0*49] = (float)a01.x; so[1*49] = (float)a01.y;
        so[2*49] = (float)a23.x; so[3*49] = (float)a23.y;
        so[4*49] = (float)a45.x; so[5*49] = (float)a45.y;
        so[6*49] = (float)a67.x; so[7*49] = (float)a67.y;
    }
    __syncthreads();

    // coalesced contiguous write: out[k][cg*32 .. cg*32+31][0..48] (terminal output -> NT ok)
    float* oslab = out + ((size_t)k * C + cg * CG) * (PH * PW);
    for (int i4 = t; i4 < (CG * 49) / 4; i4 += 256) {
        f32x4 v = *reinterpret_cast<const f32x4*>(s_out + 4 * i4);
        __builtin_nontemporal_store(v, reinterpret_cast<f32x4*>(oslab + 4 * i4));
    }
}

// ---------------- fallback (R4 kernel) if workspace too small ----------------
struct __attribute__((packed, aligned(4))) f2 { float a, b; };

__global__ __launch_bounds__(256) void roi_align_fallback(
    const float* __restrict__ feat, const float* __restrict__ rois,
    float* __restrict__ out, int K)
{
    __shared__ int   s_ylo[NS], s_yhi[NS];
    __shared__ float s_wy[NS][2];
    __shared__ int   s_xb[NS];
    __shared__ float s_wx[NS][2];

    int B   = blockIdx.x;
    int xcd = B & 7;
    int j   = B >> 3;
    int p   = j / K, k = j - p * K;
    int cb  = (p * 8 + xcd) * CGF;

    const float* r = rois + (size_t)k * 5;
    int   b  = (int)r[0];
    float x1 = r[1]*SCALE, y1 = r[2]*SCALE, x2 = r[3]*SCALE, y2 = r[4]*SCALE;
    float bw = fmaxf(x2 - x1, 1.0f) * (1.0f / PW);
    float bh = fmaxf(y2 - y1, 1.0f) * (1.0f / PH);

    int t = threadIdx.x;
    if (t < NS) {
        int ph = t >> 1, s = t & 1;
        float y = y1 + (float)ph * bh + ((float)s + 0.5f) * bh * 0.5f;
        bool v = (y >= -1.0f) && (y <= (float)H);
        float yc = fmaxf(y, 0.0f);
        int lo = (int)yc, hi;
        if (lo >= H - 1) { lo = H - 1; hi = H - 1; yc = (float)(H - 1); }
        else             { hi = lo + 1; }
        float l = yc - (float)lo;
        s_ylo[t] = lo; s_yhi[t] = hi;
        s_wy[t][0] = v ? 1.0f - l : 0.0f;
        s_wy[t][1] = v ? l        : 0.0f;
    } else if (t >= 64 && t < 64 + NS) {
        int i = t - 64, pw = i >> 1, s = i & 1;
        float x = x1 + (float)pw * bw + ((float)s + 0.5f) * bw * 0.5f;
        bool v = (x >= -1.0f) && (x <= (float)W);
        float xc = fmaxf(x, 0.0f);
        int lo = (int)xc;
        if (lo >= W - 1) {
            s_xb[i] = W - 2; s_wx[i][0] = 0.0f; s_wx[i][1] = v ? 1.0f : 0.0f;
        } else {
            float l = xc - (float)lo;
            s_xb[i] = lo; s_wx[i][0] = v ? 1.0f - l : 0.0f; s_wx[i][1] = v ? l : 0.0f;
        }
    }
    __syncthreads();

    const float* img = feat + (size_t)b * (C * H * W);
    float* out_base = out + ((size_t)k * C + cb) * (PH * PW);

    for (int i = t; i < CGF * PH * PW; i += 256) {
        int cl  = i / (PH * PW);
        int bin = i - cl * (PH * PW);
        int ph  = bin / PW;
        int pw  = bin - ph * PW;
        const float* plane = img + (size_t)(cb + cl) * (H * W);

        float acc = 0.0f;
        #pragma unroll
        for (int sy = 0; sy < 2; ++sy) {
            int ysi = 2 * ph + sy;
            const float* rlo = plane + s_ylo[ysi] * W;
            const float* rhi = plane + s_yhi[ysi] * W;
            float hy = s_wy[ysi][0], ly = s_wy[ysi][1];
            #pragma unroll
            for (int sx = 0; sx < 2; ++sx) {
                int xsi = 2 * pw + sx;
                int xb = s_xb[xsi];
                float w0 = s_wx[xsi][0], w1 = s_wx[xsi][1];
                f2 vlo = *reinterpret_cast<const f2*>(rlo + xb);
                f2 vhi = *reinterpret_cast<const f2*>(rhi + xb);
                acc += hy * (w0 * vlo.a + w1 * vlo.b)
                     + ly * (w0 * vhi.a + w1 * vhi.b);
            }
        }
        __builtin_nontemporal_store(acc * 0.25f, &out_base[i]);
    }
}

extern "C" void kernel_launch(void* const* d_in, const int* in_sizes, int n_in,
                              void* d_out, int out_size, void* d_ws, size_t ws_size,
                              hipStream_t stream) {
    const float* feat = (const float*)d_in[0];
    const float* rois = (const float*)d_in[1];
    float* out = (float*)d_out;
    int K = in_sizes[1] / 5;

    size_t need = (size_t)NCG * NB * H * W * CG * sizeof(ushort);  // ~41 MB
    if (ws_size >= need) {
        ushort* T = (ushort*)d_ws;
        int tblocks = NCG * NB * H * 7;   // 22400
        transpose_kernel<<<tblocks, 256, 0, stream>>>(feat, T);
        gather_kernel<<<K * NCG * NB, 256, 0, stream>>>(T, rois, out, K);
    } else {
        roi_align_fallback<<<K * NGROUPF, 256, 0, stream>>>(feat, rois, out, K);
    }
}

// Round 19
// 51.627 us; speedup vs baseline: 1.2710x; 1.1043x over previous
//
#include <hip/hip_runtime.h>

// RoIAlign (torchvision semantics, aligned=false, sampling_ratio=2)
// features: [N=2, C=256, H=200, W=200] f32, rois: [K,5], out: [K,256,7,7] f32
constexpr int C = 256, H = 200, W = 200, NB = 2;
constexpr int PH = 7, PW = 7;
constexpr int NS = 14;             // fallback only
constexpr float SCALE = 0.125f;
// transposed tensor: T[cg:8][nb:2][y][x][32ch] f16 — 64B per (pixel,cgroup) = 1 line
constexpr int CG = 32, NCG = C / CG;
// fallback (R4) tiling
constexpr int CGF = 8, NGROUPF = C / CGF;

typedef float    f32x4 __attribute__((ext_vector_type(4)));
typedef _Float16 h2    __attribute__((ext_vector_type(2)));

// ---- transpose: full-row blocks. One block = one (slice, y): stage 32ch x 200px in LDS,
//      zero x-tail waste, 1 barrier per 6400 elems. Regular stores (NT on producer->consumer
//      intermediate costs the consumer +16us — R15 lesson). ----
__global__ __launch_bounds__(256) void transpose_kernel(
    const float* __restrict__ feat, ushort* __restrict__ T)
{
    __shared__ float tile[W][36];   // [x][ch], pad 36: c4*4 reads stay 16B-aligned (144B rows)
    int B = blockIdx.x;
    int y = B % H;
    int s = B / H;                  // slice = cg*NB + nb
    int nb = s & 1, cg = s >> 1;

    int t = threadIdx.x;
    {
        int cl  = t >> 3;           // channel 0..31
        int xi4 = t & 7;            // float4-slot start
        const float* src = feat + (((size_t)nb * C + cg * CG + cl) * H + y) * W;
        for (int s4 = xi4; s4 < W / 4; s4 += 8) {       // 50 slots: 6-7 iters/thread
            float4 v = *reinterpret_cast<const float4*>(src + 4 * s4);
            int x = 4 * s4;
            tile[x + 0][cl] = v.x; tile[x + 1][cl] = v.y;
            tile[x + 2][cl] = v.z; tile[x + 3][cl] = v.w;
        }
    }
    __syncthreads();
    {
        int c4 = (t & 7) * 4;       // channel quad
        ushort* dstrow = T + (((size_t)s * H + y) * W) * CG;
        for (int px = t >> 3; px < W; px += 32) {       // contiguous 2KB per 32-px sweep
            float4 v = *reinterpret_cast<const float4*>(&tile[px][c4]);
            uint2 o;
            o.x = __builtin_bit_cast(uint, __builtin_amdgcn_cvt_pkrtz(v.x, v.y));
            o.y = __builtin_bit_cast(uint, __builtin_amdgcn_cvt_pkrtz(v.z, v.w));
            *reinterpret_cast<uint2*>(dstrow + px * CG + c4) = o;
        }
    }
}

// ---- gather: ALL-REGISTER corner table + MLP-16 + packed f16 FMA (R18, unchanged) ----
__global__ __launch_bounds__(256) void gather_kernel(
    const ushort* __restrict__ T, const float* __restrict__ rois,
    float* __restrict__ out, int K)
{
    __shared__ float s_out[CG * 49];   // [ch][bin] f32 — only LDS use

    int B  = blockIdx.x;
    int cg = B & 7;                 // cgroup pinned to XCD (consecutive blocks round-robin XCDs)
    int j  = B >> 3;
    int p  = j / K, k = j - p * K;  // phase p = batch slice; per-XCD L2 slice = 2.56MB resident

    const float* r = rois + (size_t)k * 5;
    int b = (int)r[0];
    if (b != p) return;             // block-uniform exit before the barrier (phantoms are cheap, R17)

    int t = threadIdx.x;
    if (t < 49 * 4) {               // 4 lanes per bin, each owns 8 channels (16B of the 64B line)
        int bin = t >> 2, q = t & 3;
        int ph = bin / 7, pw = bin - ph * 7;

        float x1 = r[1]*SCALE, y1 = r[2]*SCALE, x2 = r[3]*SCALE, y2 = r[4]*SCALE;
        float bw = fmaxf(x2 - x1, 1.0f) * (1.0f / PW);
        float bh = fmaxf(y2 - y1, 1.0f) * (1.0f / PH);

        // axis terms in registers: 2 samples per axis
        int   yr[2][2]; float wy[2][2];
        int   xr[2][2]; float wx[2][2];
        #pragma unroll
        for (int s = 0; s < 2; ++s) {
            float y = y1 + (float)ph * bh + ((float)s + 0.5f) * bh * 0.5f;
            bool v = (y >= -1.0f) && (y <= (float)H);
            float yc = fmaxf(y, 0.0f);
            int lo = (int)yc, hi;
            if (lo >= H - 1) { lo = H - 1; hi = H - 1; yc = (float)(H - 1); }
            else             { hi = lo + 1; }
            float l = yc - (float)lo;
            yr[s][0] = lo; yr[s][1] = hi;
            wy[s][0] = v ? 1.0f - l : 0.0f;
            wy[s][1] = v ? l        : 0.0f;
        }
        #pragma unroll
        for (int s = 0; s < 2; ++s) {
            float x = x1 + (float)pw * bw + ((float)s + 0.5f) * bw * 0.5f;
            bool v = (x >= -1.0f) && (x <= (float)W);
            float xc = fmaxf(x, 0.0f);
            int lo = (int)xc, hi;
            if (lo >= W - 1) { lo = W - 1; hi = W - 1; xc = (float)(W - 1); }
            else             { hi = lo + 1; }
            float l = xc - (float)lo;
            xr[s][0] = lo; xr[s][1] = hi;
            wx[s][0] = v ? 1.0f - l : 0.0f;
            wx[s][1] = v ? l        : 0.0f;
        }

        // 16 corner offsets + packed weights, fully unrolled (static indices -> registers)
        int  offv[16];
        uint wgtv[16];
        #pragma unroll
        for (int cr = 0; cr < 16; ++cr) {
            int sy = (cr >> 3) & 1, sx = (cr >> 2) & 1, cy = (cr >> 1) & 1, cx = cr & 1;
            offv[cr] = (yr[sy][cy] * W + xr[sx][cx]) * CG;
            float w = wy[sy][cy] * wx[sx][cx] * 0.25f;
            wgtv[cr] = __builtin_bit_cast(uint, __builtin_amdgcn_cvt_pkrtz(w, w));
        }

        const ushort* slab = T + ((size_t)(cg * NB + p) * H * W) * CG + q * 8;
        // issue ALL 16 corner loads (MLP=16) — no barriers, no LDS on the path
        uint4 d[16];
        #pragma unroll
        for (int cr = 0; cr < 16; ++cr)
            d[cr] = *reinterpret_cast<const uint4*>(slab + offv[cr]);

        h2 a01 = {0, 0}, a23 = {0, 0}, a45 = {0, 0}, a67 = {0, 0};
        #define H2(u) (__builtin_bit_cast(h2, (uint)(u)))
        #pragma unroll
        for (int cr = 0; cr < 16; ++cr) {
            h2 wpk = H2(wgtv[cr]);
            a01 += H2(d[cr].x) * wpk;  a23 += H2(d[cr].y) * wpk;
            a45 += H2(d[cr].z) * wpk;  a67 += H2(d[cr].w) * wpk;
        }
        #undef H2

        float* so = s_out + (8 * q) * 49 + bin;
        so[0*49] = (float)a01.x; so[1*49] = (float)a01.y;
        so[2*49] = (float)a23.x; so[3*49] = (float)a23.y;
        so[4*49] = (float)a45.x; so[5*49] = (float)a45.y;
        so[6*49] = (float)a67.x; so[7*49] = (float)a67.y;
    }
    __syncthreads();

    // coalesced contiguous write: out[k][cg*32 .. cg*32+31][0..48] (terminal output -> NT ok)
    float* oslab = out + ((size_t)k * C + cg * CG) * (PH * PW);
    for (int i4 = t; i4 < (CG * 49) / 4; i4 += 256) {
        f32x4 v = *reinterpret_cast<const f32x4*>(s_out + 4 * i4);
        __builtin_nontemporal_store(v, reinterpret_cast<f32x4*>(oslab + 4 * i4));
    }
}

// ---------------- fallback (R4 kernel) if workspace too small ----------------
struct __attribute__((packed, aligned(4))) f2 { float a, b; };

__global__ __launch_bounds__(256) void roi_align_fallback(
    const float* __restrict__ feat, const float* __restrict__ rois,
    float* __restrict__ out, int K)
{
    __shared__ int   s_ylo[NS], s_yhi[NS];
    __shared__ float s_wy[NS][2];
    __shared__ int   s_xb[NS];
    __shared__ float s_wx[NS][2];

    int B   = blockIdx.x;
    int xcd = B & 7;
    int j   = B >> 3;
    int p   = j / K, k = j - p * K;
    int cb  = (p * 8 + xcd) * CGF;

    const float* r = rois + (size_t)k * 5;
    int   b  = (int)r[0];
    float x1 = r[1]*SCALE, y1 = r[2]*SCALE, x2 = r[3]*SCALE, y2 = r[4]*SCALE;
    float bw = fmaxf(x2 - x1, 1.0f) * (1.0f / PW);
    float bh = fmaxf(y2 - y1, 1.0f) * (1.0f / PH);

    int t = threadIdx.x;
    if (t < NS) {
        int ph = t >> 1, s = t & 1;
        float y = y1 + (float)ph * bh + ((float)s + 0.5f) * bh * 0.5f;
        bool v = (y >= -1.0f) && (y <= (float)H);
        float yc = fmaxf(y, 0.0f);
        int lo = (int)yc, hi;
        if (lo >= H - 1) { lo = H - 1; hi = H - 1; yc = (float)(H - 1); }
        else             { hi = lo + 1; }
        float l = yc - (float)lo;
        s_ylo[t] = lo; s_yhi[t] = hi;
        s_wy[t][0] = v ? 1.0f - l : 0.0f;
        s_wy[t][1] = v ? l        : 0.0f;
    } else if (t >= 64 && t < 64 + NS) {
        int i = t - 64, pw = i >> 1, s = i & 1;
        float x = x1 + (float)pw * bw + ((float)s + 0.5f) * bw * 0.5f;
        bool v = (x >= -1.0f) && (x <= (float)W);
        float xc = fmaxf(x, 0.0f);
        int lo = (int)xc;
        if (lo >= W - 1) {
            s_xb[i] = W - 2; s_wx[i][0] = 0.0f; s_wx[i][1] = v ? 1.0f : 0.0f;
        } else {
            float l = xc - (float)lo;
            s_xb[i] = lo; s_wx[i][0] = v ? 1.0f - l : 0.0f; s_wx[i][1] = v ? l : 0.0f;
        }
    }
    __syncthreads();

    const float* img = feat + (size_t)b * (C * H * W);
    float* out_base = out + ((size_t)k * C + cb) * (PH * PW);

    for (int i = t; i < CGF * PH * PW; i += 256) {
        int cl  = i / (PH * PW);
        int bin = i - cl * (PH * PW);
        int ph  = bin / PW;
        int pw  = bin - ph * PW;
        const float* plane = img + (size_t)(cb + cl) * (H * W);

        float acc = 0.0f;
        #pragma unroll
        for (int sy = 0; sy < 2; ++sy) {
            int ysi = 2 * ph + sy;
            const float* rlo = plane + s_ylo[ysi] * W;
            const float* rhi = plane + s_yhi[ysi] * W;
            float hy = s_wy[ysi][0], ly = s_wy[ysi][1];
            #pragma unroll
            for (int sx = 0; sx < 2; ++sx) {
                int xsi = 2 * pw + sx;
                int xb = s_xb[xsi];
                float w0 = s_wx[xsi][0], w1 = s_wx[xsi][1];
                f2 vlo = *reinterpret_cast<const f2*>(rlo + xb);
                f2 vhi = *reinterpret_cast<const f2*>(rhi + xb);
                acc += hy * (w0 * vlo.a + w1 * vlo.b)
                     + ly * (w0 * vhi.a + w1 * vhi.b);
            }
        }
        __builtin_nontemporal_store(acc * 0.25f, &out_base[i]);
    }
}

extern "C" void kernel_launch(void* const* d_in, const int* in_sizes, int n_in,
                              void* d_out, int out_size, void* d_ws, size_t ws_size,
                              hipStream_t stream) {
    const float* feat = (const float*)d_in[0];
    const float* rois = (const float*)d_in[1];
    float* out = (float*)d_out;
    int K = in_sizes[1] / 5;

    size_t need = (size_t)NCG * NB * H * W * CG * sizeof(ushort);  // ~41 MB
    if (ws_size >= need) {
        ushort* T = (ushort*)d_ws;
        int tblocks = NCG * NB * H;   // 3200 full-row blocks
        transpose_kernel<<<tblocks, 256, 0, stream>>>(feat, T);
        gather_kernel<<<K * NCG * NB, 256, 0, stream>>>(T, rois, out, K);
    } else {
        roi_align_fallback<<<K * NGROUPF, 256, 0, stream>>>(feat, rois, out, K);
    }
}